// Round 6
// baseline (2717.216 us; speedup 1.0000x reference)
//
#include <hip/hip_runtime.h>
#include <math.h>

#define NB   2048
#define DIN  784
#define HN   256
#define NOUT 10
#define OSTR (HN + HN + NOUT)   // 522

// Per-block LDS: 4 batch rows (one wave each). All fp32.
struct Smem {
  float pl [4][HN];    // parent logits (pl1 for layer-0 scan, then pl2)
  float h1o[4][HN];    // h1 old (0/1)
  float h2o[4][HN];    // h2 old
  float h1n[4][HN];    // h1 new
  float uu [4][HN];    // staged uniforms (u1, then u2)
  float tmp[4][HN];    // nl-init redistribution buffer
};

// ---- bitwise replica of numpy's SIMD float32 exp ---------------------------
// (loops_exponent_log.dispatch.c.src: magic-rint, Cody-Waite ln2 split,
//  rational P5(x)/Q2(x), IEEE divide, 2^q scale.)
__device__ __forceinline__ float np_expf(float xf) {
  float q = __fmul_rn(xf, 1.442695040888963f);       // x * NPY_LOG2Ef
  q = __fadd_rn(q, 12582912.0f);                     // 0x1.8p23 round-to-even
  q = __fsub_rn(q, 12582912.0f);
  float x = __builtin_fmaf(q, -6.93145752e-1f, xf);  // Cody-Waite high
  x = __builtin_fmaf(q, -1.42860677e-6f, x);         // Cody-Waite low
  float num = __builtin_fmaf(x, 5.082762527590693718096e-04f,
                                6.757896990527504603057e-03f);
  num = __builtin_fmaf(num, x, 5.114512081637298353406e-02f);
  num = __builtin_fmaf(num, x, 2.473615434895520810817e-01f);
  num = __builtin_fmaf(num, x, 7.257664613233124478488e-01f);
  num = __builtin_fmaf(num, x, 9.999999999980870924916e-01f);
  float den = __builtin_fmaf(x, 2.159509375685829852307e-02f,
                                -2.742335390411667452936e-01f);
  den = __builtin_fmaf(den, x, 1.0f);
  float r = __fdiv_rn(num, den);
  int qi = (int)q;                                   // |q| small in our range
  return __fmul_rn(r, __int_as_float((qi + 127) << 23));
}

// log1p: correctly-rounded fp32 via fp64 ocml (HIP header device overload —
// __builtin_log1p does NOT link on amdgcn)
__device__ __forceinline__ float np_log1pf(float e) {
  return (float)log1p((double)e);
}

// sigmoid-CE, numpy op order: (max(l,0) - l*label) + log1p(exp(-|l|))
__device__ __forceinline__ float ce32(float l, float label) {
  float t3 = __fsub_rn(fmaxf(l, 0.0f), __fmul_rn(l, label));
  return __fadd_rn(t3, np_log1pf(np_expf(-fabsf(l))));
}

// sigmoid = 1/(1+np.exp(-z)), IEEE divide
__device__ __forceinline__ float sig32(float z) {
  return __fdiv_rn(1.0f, __fadd_rn(1.0f, np_expf(-z)));
}

// numpy pairwise sum over 10 elements on lanes 0..9 (uniform result):
// ((c0+c1)+(c2+c3))+((c4+c5)+(c6+c7)), then +c8, +c9
__device__ __forceinline__ float sum10(float c) {
  float c0 = __shfl(c, 0), c1 = __shfl(c, 1), c2 = __shfl(c, 2), c3 = __shfl(c, 3);
  float c4 = __shfl(c, 4), c5 = __shfl(c, 5), c6 = __shfl(c, 6), c7 = __shfl(c, 7);
  float c8 = __shfl(c, 8), c9 = __shfl(c, 9);
  float t = __fadd_rn(__fadd_rn(__fadd_rn(c0, c1), __fadd_rn(c2, c3)),
                      __fadd_rn(__fadd_rn(c4, c5), __fadd_rn(c6, c7)));
  t = __fadd_rn(t, c8);
  t = __fadd_rn(t, c9);
  return t;
}

__global__ __launch_bounds__(256) void stoch_mlp(
    const float* __restrict__ x,  const int* __restrict__ h1,
    const int* __restrict__ h2,   const int* __restrict__ y,
    const float* __restrict__ W1, const float* __restrict__ b1,
    const float* __restrict__ W2, const float* __restrict__ b2,
    const float* __restrict__ Wo, const float* __restrict__ bo,
    const float* __restrict__ u1, const float* __restrict__ u2,
    float* __restrict__ out)
{
  __shared__ Smem sm;
  const int t    = threadIdx.x;
  const int lane = t & 63;
  const int wid  = t >> 6;            // wave id == local batch row
  const int b0   = blockIdx.x * 4;
  const int b    = b0 + wid;

  // ---- phase 1: stage states + uniforms; pl1 = x@W1 (BLAS-faithful fp32) --
  for (int j = lane; j < HN; j += 64) {
    sm.h1o[wid][j] = (float)h1[b * HN + j];
    sm.h2o[wid][j] = (float)h2[b * HN + j];
    sm.uu [wid][j] = u1[(size_t)j * NB + b];
  }
  {
    float a0 = 0.0f, a1 = 0.0f, a2 = 0.0f, a3 = 0.0f;   // sequential-k FMA chain
    const float* x0 = x + (size_t)b0 * DIN;
    for (int k = 0; k < DIN; ++k) {
      float wk = W1[k * HN + t];
      a0 = __builtin_fmaf(x0[k],           wk, a0);
      a1 = __builtin_fmaf(x0[DIN   + k],   wk, a1);
      a2 = __builtin_fmaf(x0[2*DIN + k],   wk, a2);
      a3 = __builtin_fmaf(x0[3*DIN + k],   wk, a3);
    }
    sm.pl[0][t] = __fadd_rn(a0, b1[t]);
    sm.pl[1][t] = __fadd_rn(a1, b1[t]);
    sm.pl[2][t] = __fadd_rn(a2, b1[t]);
    sm.pl[3][t] = __fadd_rn(a3, b1[t]);
  }
  __syncthreads();

  // nl-init = h1_old @ W2 + b2: masked fp32 adds == BLAS FMA chain bitwise
  {
    float acc[4] = {0.0f, 0.0f, 0.0f, 0.0f};
    for (int j = 0; j < HN; ++j) {
      if (sm.h1o[wid][j] != 0.0f) {
        float4 wf = *reinterpret_cast<const float4*>(W2 + (size_t)j * HN + 4*lane);
        acc[0] = __fadd_rn(acc[0], wf.x);  acc[1] = __fadd_rn(acc[1], wf.y);
        acc[2] = __fadd_rn(acc[2], wf.z);  acc[3] = __fadd_rn(acc[3], wf.w);
      }
    }
    float4 bv = *reinterpret_cast<const float4*>(b2 + 4*lane);
    sm.tmp[wid][4*lane + 0] = __fadd_rn(acc[0], bv.x);
    sm.tmp[wid][4*lane + 1] = __fadd_rn(acc[1], bv.y);
    sm.tmp[wid][4*lane + 2] = __fadd_rn(acc[2], bv.z);
    sm.tmp[wid][4*lane + 3] = __fadd_rn(acc[3], bv.w);
  }
  __syncthreads();

  // ---- phase 2: layer-0 scan, numpy-pairwise-exact fp32 -------------------
  // lane -> (side, half, jacc): children k_m = half*128 + m*8 + jacc, m=0..15
  const int idx  = lane & 15;
  const int half = idx >> 3;
  const int jacc = idx & 7;
  const int side = (lane >> 4) & 1;
  const int kbase = half * 128 + jacc;

  float nlv[16], nvv[16], cc[16], wv[16];
  #pragma unroll
  for (int m = 0; m < 16; ++m) {
    nlv[m] = sm.tmp[wid][kbase + m*8];
    nvv[m] = sm.h2o[wid][kbase + m*8];
    cc[m]  = ce32(nlv[m], nvv[m]);       // cached CE of carried logits
    wv[m]  = W2[kbase + m*8];            // prefetch row 0
  }

  for (int j = 0; j < HN; ++j) {
    float node = sm.h1o[wid][j];
    float uj   = sm.uu[wid][j];
    float plj  = sm.pl[wid][j];
    bool  nd   = (node != 0.0f);
    float wcur[16];
    #pragma unroll
    for (int m = 0; m < 16; ++m) wcur[m] = wv[m];
    if (j + 1 < HN) {
      #pragma unroll
      for (int m = 0; m < 16; ++m) wv[m] = W2[(size_t)(j + 1) * HN + kbase + m*8];
    }
    float one_m = __fsub_rn(1.0f, node);
    float nl0[16], nl1[16], chg[16];
    // changed side: nl0 if node==1 else nl1; the other side is bitwise == nlv
    #pragma unroll
    for (int m = 0; m < 16; ++m) {
      nl0[m] = __fsub_rn(nlv[m], __fmul_rn(node,  wcur[m]));
      nl1[m] = __fadd_rn(nlv[m], __fmul_rn(one_m, wcur[m]));
      chg[m] = ce32(nd ? nl0[m] : nl1[m], nvv[m]);
    }
    // my side's 16-term sequential accumulator (numpy 8-acc pairwise order)
    bool my_fresh = ((side == 0) == nd);
    float r = 0.0f;
    #pragma unroll
    for (int m = 0; m < 16; ++m) {
      float c = my_fresh ? chg[m] : cc[m];
      r = (m == 0) ? c : __fadd_rn(r, c);
    }
    r = __fadd_rn(r, __shfl_xor(r, 1));   // ((r0+r1)+(r2+r3))+((r4+r5)+(r6+r7))
    r = __fadd_rn(r, __shfl_xor(r, 2));
    r = __fadd_rn(r, __shfl_xor(r, 4));
    r = __fadd_rn(r, __shfl_xor(r, 8));   // left half + right half
    float S0 = __shfl(r, 0);
    float S1 = __shfl(r, 16);
    float z    = __fsub_rn(__fadd_rn(plj, -S1), -S0);   // (pl + lp1) - lp0
    float prob = sig32(z);
    bool  nw   = (uj < prob);
    bool  sel_changed = (nw != nd);
    #pragma unroll
    for (int m = 0; m < 16; ++m) {
      nlv[m] = nw ? nl1[m] : nl0[m];
      cc[m]  = sel_changed ? chg[m] : cc[m];
    }
    if (lane == 0) sm.h1n[wid][j] = nw ? 1.0f : 0.0f;
  }
  __syncthreads();

  // ---- phase 3: pl2 = h1_new @ W2 + b2 (masked fp32 == BLAS chain) --------
  {
    float acc[4] = {0.0f, 0.0f, 0.0f, 0.0f};
    for (int j = 0; j < HN; ++j) {
      if (sm.h1n[wid][j] != 0.0f) {
        float4 wf = *reinterpret_cast<const float4*>(W2 + (size_t)j * HN + 4*lane);
        acc[0] = __fadd_rn(acc[0], wf.x);  acc[1] = __fadd_rn(acc[1], wf.y);
        acc[2] = __fadd_rn(acc[2], wf.z);  acc[3] = __fadd_rn(acc[3], wf.w);
      }
    }
    float4 bv = *reinterpret_cast<const float4*>(b2 + 4*lane);
    sm.pl[wid][4*lane + 0] = __fadd_rn(acc[0], bv.x);
    sm.pl[wid][4*lane + 1] = __fadd_rn(acc[1], bv.y);
    sm.pl[wid][4*lane + 2] = __fadd_rn(acc[2], bv.z);
    sm.pl[wid][4*lane + 3] = __fadd_rn(acc[3], bv.w);
  }
  for (int j = lane; j < HN; j += 64) sm.uu[wid][j] = u2[(size_t)j * NB + b];

  // layer-1 init: nlo = h2_old @ Wout + bout (masked fp32); nvy = y
  float nvy = 0.0f, nlo = 0.0f;
  if (lane < NOUT) {
    nvy = (float)y[b * NOUT + lane];
    float a = 0.0f;
    for (int j = 0; j < HN; ++j)
      if (sm.h2o[wid][j] != 0.0f) a = __fadd_rn(a, Wo[j * NOUT + lane]);
    nlo = __fadd_rn(a, bo[lane]);
  }
  float c1c = (lane < NOUT) ? ce32(nlo, nvy) : 0.0f;   // cached CE
  __syncthreads();

  // ---- phase 4: layer-1 scan (10 children on lanes 0..9) ------------------
  {
    float wnext = (lane < NOUT) ? Wo[lane] : 0.0f;
    for (int j = 0; j < HN; ++j) {
      float node = sm.h2o[wid][j];
      float uj   = sm.uu[wid][j];
      float plj  = sm.pl[wid][j];
      bool  nd   = (node != 0.0f);
      float w    = wnext;
      if (j + 1 < HN) wnext = (lane < NOUT) ? Wo[(j + 1) * NOUT + lane] : 0.0f;
      float one_m = __fsub_rn(1.0f, node);
      float nl0 = __fsub_rn(nlo, __fmul_rn(node,  w));
      float nl1 = __fadd_rn(nlo, __fmul_rn(one_m, w));
      float chg = (lane < NOUT) ? ce32(nd ? nl0 : nl1, nvy) : 0.0f;
      float c0 = nd ? chg : c1c;
      float c1 = nd ? c1c : chg;
      float S0 = sum10(c0);
      float S1 = sum10(c1);
      float z    = __fsub_rn(__fadd_rn(plj, -S1), -S0);
      float prob = sig32(z);
      bool  nw   = (uj < prob);
      bool  sel_changed = (nw != nd);
      nlo = nw ? nl1 : nl0;
      c1c = sel_changed ? chg : c1c;
      if (lane == 0) out[(size_t)b * OSTR + HN + j] = nw ? 1.0f : 0.0f;
    }
  }

  // ---- phase 5: outputs ---------------------------------------------------
  float* orow = out + (size_t)b * OSTR;
  for (int j = lane; j < HN; j += 64) orow[j] = sm.h1n[wid][j];
  if (lane < NOUT) orow[2*HN + lane] = nlo;
}

extern "C" void kernel_launch(void* const* d_in, const int* in_sizes, int n_in,
                              void* d_out, int out_size, void* d_ws, size_t ws_size,
                              hipStream_t stream) {
  const float* x  = (const float*)d_in[0];
  const int*   h1 = (const int*)  d_in[1];
  const int*   h2 = (const int*)  d_in[2];
  const int*   y  = (const int*)  d_in[3];
  const float* W1 = (const float*)d_in[4];
  const float* b1 = (const float*)d_in[5];
  const float* W2 = (const float*)d_in[6];
  const float* b2 = (const float*)d_in[7];
  const float* Wo = (const float*)d_in[8];
  const float* bo = (const float*)d_in[9];
  const float* u1 = (const float*)d_in[10];
  const float* u2 = (const float*)d_in[11];
  stoch_mlp<<<NB/4, 256, 0, stream>>>(x, h1, h2, y, W1, b1, W2, b2, Wo, bo, u1, u2,
                                      (float*)d_out);
}

// Round 7
// 1077.536 us; speedup vs baseline: 2.5217x; 2.5217x over previous
//
#include <hip/hip_runtime.h>
#include <math.h>

#define NB   2048
#define DIN  784
#define HN   256
#define NOUT 10
#define OSTR (HN + HN + NOUT)   // 522

// Per-block LDS: 4 batch rows (one wave each). All fp32.
struct Smem {
  float pl [4][HN];    // parent logits (pl1 for layer-0 scan, then pl2)
  float h1o[4][HN];    // h1 old (0/1)
  float h2o[4][HN];    // h2 old
  float h1n[4][HN];    // h1 new
  float uu [4][HN];    // staged uniforms (u1, then u2)
  float tmp[4][HN];    // nl-init redistribution buffer
};

// ---- bitwise replica of numpy's SIMD float32 exp ---------------------------
__device__ __forceinline__ float np_expf(float xf) {
  float q = __fmul_rn(xf, 1.442695040888963f);       // x * NPY_LOG2Ef
  q = __fadd_rn(q, 12582912.0f);                     // 0x1.8p23 round-to-even
  q = __fsub_rn(q, 12582912.0f);
  float x = __builtin_fmaf(q, -6.93145752e-1f, xf);  // Cody-Waite high
  x = __builtin_fmaf(q, -1.42860677e-6f, x);         // Cody-Waite low
  float num = __builtin_fmaf(x, 5.082762527590693718096e-04f,
                                6.757896990527504603057e-03f);
  num = __builtin_fmaf(num, x, 5.114512081637298353406e-02f);
  num = __builtin_fmaf(num, x, 2.473615434895520810817e-01f);
  num = __builtin_fmaf(num, x, 7.257664613233124478488e-01f);
  num = __builtin_fmaf(num, x, 9.999999999980870924916e-01f);
  float den = __builtin_fmaf(x, 2.159509375685829852307e-02f,
                                -2.742335390411667452936e-01f);
  den = __builtin_fmaf(den, x, 1.0f);
  float r = __fdiv_rn(num, den);
  int qi = (int)q;
  return __fmul_rn(r, __int_as_float((qi + 127) << 23));
}

// log1p: correctly-rounded fp32 via fp64 ocml (same as passing round 6)
__device__ __forceinline__ float np_log1pf(float e) {
  return (float)log1p((double)e);
}

// sigmoid-CE, numpy op order: (max(l,0) - l*label) + log1p(exp(-|l|))
__device__ __forceinline__ float ce32(float l, float label) {
  float t3 = __fsub_rn(fmaxf(l, 0.0f), __fmul_rn(l, label));
  return __fadd_rn(t3, np_log1pf(np_expf(-fabsf(l))));
}

// sigmoid = 1/(1+np.exp(-z)), IEEE divide
__device__ __forceinline__ float sig32(float z) {
  return __fdiv_rn(1.0f, __fadd_rn(1.0f, np_expf(-z)));
}

// numpy pairwise sum over 10 on lanes 0..9 (uniform result)
__device__ __forceinline__ float sum10(float c) {
  float c0 = __shfl(c, 0), c1 = __shfl(c, 1), c2 = __shfl(c, 2), c3 = __shfl(c, 3);
  float c4 = __shfl(c, 4), c5 = __shfl(c, 5), c6 = __shfl(c, 6), c7 = __shfl(c, 7);
  float c8 = __shfl(c, 8), c9 = __shfl(c, 9);
  float t = __fadd_rn(__fadd_rn(__fadd_rn(c0, c1), __fadd_rn(c2, c3)),
                      __fadd_rn(__fadd_rn(c4, c5), __fadd_rn(c6, c7)));
  t = __fadd_rn(t, c8);
  t = __fadd_rn(t, c9);
  return t;
}

// numpy pairwise sum over 256 children distributed 4/lane.
// Lane l = 16*g + idx holds chain idx's terms m = 4g..4g+3 in c[0..3].
// Chain fold: strict left fold over m=0..15 (numpy 8-accumulator chain of 16),
// then butterfly combine = ((r0+r1)+(r2+r3))+((r4+r5)+(r6+r7)) per half,
// then half0+half1. Bitwise identical on all 64 lanes.
__device__ __forceinline__ float fold256(const float c[4], int idx) {
  float r = __shfl(c[0], idx);
  r = __fadd_rn(r, __shfl(c[1], idx));
  r = __fadd_rn(r, __shfl(c[2], idx));
  r = __fadd_rn(r, __shfl(c[3], idx));
  r = __fadd_rn(r, __shfl(c[0], idx + 16));
  r = __fadd_rn(r, __shfl(c[1], idx + 16));
  r = __fadd_rn(r, __shfl(c[2], idx + 16));
  r = __fadd_rn(r, __shfl(c[3], idx + 16));
  r = __fadd_rn(r, __shfl(c[0], idx + 32));
  r = __fadd_rn(r, __shfl(c[1], idx + 32));
  r = __fadd_rn(r, __shfl(c[2], idx + 32));
  r = __fadd_rn(r, __shfl(c[3], idx + 32));
  r = __fadd_rn(r, __shfl(c[0], idx + 48));
  r = __fadd_rn(r, __shfl(c[1], idx + 48));
  r = __fadd_rn(r, __shfl(c[2], idx + 48));
  r = __fadd_rn(r, __shfl(c[3], idx + 48));
  r = __fadd_rn(r, __shfl_xor(r, 1));
  r = __fadd_rn(r, __shfl_xor(r, 2));
  r = __fadd_rn(r, __shfl_xor(r, 4));
  r = __fadd_rn(r, __shfl_xor(r, 8));
  return r;
}

__global__ __launch_bounds__(256) void stoch_mlp(
    const float* __restrict__ x,  const int* __restrict__ h1,
    const int* __restrict__ h2,   const int* __restrict__ y,
    const float* __restrict__ W1, const float* __restrict__ b1,
    const float* __restrict__ W2, const float* __restrict__ b2,
    const float* __restrict__ Wo, const float* __restrict__ bo,
    const float* __restrict__ u1, const float* __restrict__ u2,
    float* __restrict__ out)
{
  __shared__ Smem sm;
  const int t    = threadIdx.x;
  const int lane = t & 63;
  const int wid  = t >> 6;            // wave id == local batch row
  const int b0   = blockIdx.x * 4;
  const int b    = b0 + wid;

  // ---- phase 1: stage states + uniforms; pl1 = x@W1 (BLAS-faithful fp32) --
  for (int j = lane; j < HN; j += 64) {
    sm.h1o[wid][j] = (float)h1[b * HN + j];
    sm.h2o[wid][j] = (float)h2[b * HN + j];
    sm.uu [wid][j] = u1[(size_t)j * NB + b];
  }
  {
    float a0 = 0.0f, a1 = 0.0f, a2 = 0.0f, a3 = 0.0f;   // sequential-k FMA chain
    const float* x0 = x + (size_t)b0 * DIN;
    for (int k = 0; k < DIN; ++k) {
      float wk = W1[k * HN + t];
      a0 = __builtin_fmaf(x0[k],           wk, a0);
      a1 = __builtin_fmaf(x0[DIN   + k],   wk, a1);
      a2 = __builtin_fmaf(x0[2*DIN + k],   wk, a2);
      a3 = __builtin_fmaf(x0[3*DIN + k],   wk, a3);
    }
    sm.pl[0][t] = __fadd_rn(a0, b1[t]);
    sm.pl[1][t] = __fadd_rn(a1, b1[t]);
    sm.pl[2][t] = __fadd_rn(a2, b1[t]);
    sm.pl[3][t] = __fadd_rn(a3, b1[t]);
  }
  __syncthreads();

  // nl-init = h1_old @ W2 + b2: masked fp32 adds == BLAS FMA chain bitwise
  {
    float acc[4] = {0.0f, 0.0f, 0.0f, 0.0f};
    for (int j = 0; j < HN; ++j) {
      if (sm.h1o[wid][j] != 0.0f) {
        float4 wf = *reinterpret_cast<const float4*>(W2 + (size_t)j * HN + 4*lane);
        acc[0] = __fadd_rn(acc[0], wf.x);  acc[1] = __fadd_rn(acc[1], wf.y);
        acc[2] = __fadd_rn(acc[2], wf.z);  acc[3] = __fadd_rn(acc[3], wf.w);
      }
    }
    float4 bv = *reinterpret_cast<const float4*>(b2 + 4*lane);
    sm.tmp[wid][4*lane + 0] = __fadd_rn(acc[0], bv.x);
    sm.tmp[wid][4*lane + 1] = __fadd_rn(acc[1], bv.y);
    sm.tmp[wid][4*lane + 2] = __fadd_rn(acc[2], bv.z);
    sm.tmp[wid][4*lane + 3] = __fadd_rn(acc[3], bv.w);
  }
  __syncthreads();

  // ---- phase 2: layer-0 scan — 4 children per lane ------------------------
  // lane = 16*g + idx; chain idx = (half, jacc); this lane owns m = 4g..4g+3:
  // child k(i) = half*128 + (4g+i)*8 + jacc
  const int idx  = lane & 15;
  const int g    = lane >> 4;
  const int half = idx >> 3;
  const int jacc = idx & 7;
  const int kb   = half * 128 + (4 * g) * 8 + jacc;   // + i*8

  float nlv[4], nv[4], wv[4];
  #pragma unroll
  for (int i = 0; i < 4; ++i) {
    int k = kb + i * 8;
    nlv[i] = sm.tmp[wid][k];
    nv[i]  = sm.h2o[wid][k];
    wv[i]  = W2[k];                    // prefetch row 0
  }
  float S_c;                           // carried-state CE sum (wave-uniform)
  {
    float ci[4];
    #pragma unroll
    for (int i = 0; i < 4; ++i) ci[i] = ce32(nlv[i], nv[i]);
    S_c = fold256(ci, idx);
  }

  {
    float nodeN = sm.h1o[wid][0], uN = sm.uu[wid][0], plN = sm.pl[wid][0];
    for (int j = 0; j < HN; ++j) {
      float node = nodeN, uj = uN, plj = plN;
      bool  nd   = (node != 0.0f);
      float wcur[4];
      #pragma unroll
      for (int i = 0; i < 4; ++i) wcur[i] = wv[i];
      if (j + 1 < HN) {
        nodeN = sm.h1o[wid][j + 1];
        uN    = sm.uu [wid][j + 1];
        plN   = sm.pl [wid][j + 1];
        #pragma unroll
        for (int i = 0; i < 4; ++i) wv[i] = W2[(size_t)(j + 1) * HN + kb + i * 8];
      }
      float one_m = __fsub_rn(1.0f, node);
      float nl0[4], nl1[4], chg[4];
      #pragma unroll
      for (int i = 0; i < 4; ++i) {
        nl0[i] = __fsub_rn(nlv[i], __fmul_rn(node,  wcur[i]));
        nl1[i] = __fadd_rn(nlv[i], __fmul_rn(one_m, wcur[i]));
        chg[i] = ce32(nd ? nl0[i] : nl1[i], nv[i]);   // fresh side only
      }
      float F  = fold256(chg, idx);    // fresh-side CE sum, numpy order
      float S0 = nd ? F : S_c;         // stale side == carried sum bitwise
      float S1 = nd ? S_c : F;
      float z    = __fsub_rn(__fadd_rn(plj, -S1), -S0);   // (pl + lp1) - lp0
      float prob = sig32(z);
      bool  nw   = (uj < prob);
      #pragma unroll
      for (int i = 0; i < 4; ++i) nlv[i] = nw ? nl1[i] : nl0[i];
      S_c = (nw != nd) ? F : S_c;
      if (lane == 0) sm.h1n[wid][j] = nw ? 1.0f : 0.0f;
    }
  }
  __syncthreads();

  // ---- phase 3: pl2 = h1_new @ W2 + b2 (masked fp32 == BLAS chain) --------
  {
    float acc[4] = {0.0f, 0.0f, 0.0f, 0.0f};
    for (int j = 0; j < HN; ++j) {
      if (sm.h1n[wid][j] != 0.0f) {
        float4 wf = *reinterpret_cast<const float4*>(W2 + (size_t)j * HN + 4*lane);
        acc[0] = __fadd_rn(acc[0], wf.x);  acc[1] = __fadd_rn(acc[1], wf.y);
        acc[2] = __fadd_rn(acc[2], wf.z);  acc[3] = __fadd_rn(acc[3], wf.w);
      }
    }
    float4 bv = *reinterpret_cast<const float4*>(b2 + 4*lane);
    sm.pl[wid][4*lane + 0] = __fadd_rn(acc[0], bv.x);
    sm.pl[wid][4*lane + 1] = __fadd_rn(acc[1], bv.y);
    sm.pl[wid][4*lane + 2] = __fadd_rn(acc[2], bv.z);
    sm.pl[wid][4*lane + 3] = __fadd_rn(acc[3], bv.w);
  }
  for (int j = lane; j < HN; j += 64) sm.uu[wid][j] = u2[(size_t)j * NB + b];

  // layer-1 init: nlo = h2_old @ Wout + bout (masked fp32); nvy = y
  float nvy = 0.0f, nlo = 0.0f;
  if (lane < NOUT) {
    nvy = (float)y[b * NOUT + lane];
    float a = 0.0f;
    for (int j = 0; j < HN; ++j)
      if (sm.h2o[wid][j] != 0.0f) a = __fadd_rn(a, Wo[j * NOUT + lane]);
    nlo = __fadd_rn(a, bo[lane]);
  }
  float S_c1 = sum10((lane < NOUT) ? ce32(nlo, nvy) : 0.0f);
  __syncthreads();

  // ---- phase 4: layer-1 scan (10 children on lanes 0..9) ------------------
  {
    float wnext = (lane < NOUT) ? Wo[lane] : 0.0f;
    for (int j = 0; j < HN; ++j) {
      float node = sm.h2o[wid][j];
      float uj   = sm.uu[wid][j];
      float plj  = sm.pl[wid][j];
      bool  nd   = (node != 0.0f);
      float w    = wnext;
      if (j + 1 < HN) wnext = (lane < NOUT) ? Wo[(j + 1) * NOUT + lane] : 0.0f;
      float one_m = __fsub_rn(1.0f, node);
      float nl0 = __fsub_rn(nlo, __fmul_rn(node,  w));
      float nl1 = __fadd_rn(nlo, __fmul_rn(one_m, w));
      float chg = (lane < NOUT) ? ce32(nd ? nl0 : nl1, nvy) : 0.0f;
      float F   = sum10(chg);
      float S0  = nd ? F : S_c1;
      float S1  = nd ? S_c1 : F;
      float z    = __fsub_rn(__fadd_rn(plj, -S1), -S0);
      float prob = sig32(z);
      bool  nw   = (uj < prob);
      nlo  = nw ? nl1 : nl0;
      S_c1 = (nw != nd) ? F : S_c1;
      if (lane == 0) out[(size_t)b * OSTR + HN + j] = nw ? 1.0f : 0.0f;
    }
  }

  // ---- phase 5: outputs ---------------------------------------------------
  float* orow = out + (size_t)b * OSTR;
  for (int j = lane; j < HN; j += 64) orow[j] = sm.h1n[wid][j];
  if (lane < NOUT) orow[2*HN + lane] = nlo;
}

extern "C" void kernel_launch(void* const* d_in, const int* in_sizes, int n_in,
                              void* d_out, int out_size, void* d_ws, size_t ws_size,
                              hipStream_t stream) {
  const float* x  = (const float*)d_in[0];
  const int*   h1 = (const int*)  d_in[1];
  const int*   h2 = (const int*)  d_in[2];
  const int*   y  = (const int*)  d_in[3];
  const float* W1 = (const float*)d_in[4];
  const float* b1 = (const float*)d_in[5];
  const float* W2 = (const float*)d_in[6];
  const float* b2 = (const float*)d_in[7];
  const float* Wo = (const float*)d_in[8];
  const float* bo = (const float*)d_in[9];
  const float* u1 = (const float*)d_in[10];
  const float* u2 = (const float*)d_in[11];
  stoch_mlp<<<NB/4, 256, 0, stream>>>(x, h1, h2, y, W1, b1, W2, b2, Wo, bo, u1, u2,
                                      (float*)d_out);
}

// Round 8
// 682.873 us; speedup vs baseline: 3.9791x; 1.5779x over previous
//
#include <hip/hip_runtime.h>
#include <math.h>

#define NB   2048
#define DIN  784
#define HN   256
#define NOUT 10
#define OSTR (HN + HN + NOUT)   // 522

// Per-block LDS: 4 batch rows (one wave each) + fp64 log tables.
struct Smem {
  float pl [4][HN];    // parent logits (pl1 for layer-0 scan, then pl2)
  float h1o[4][HN];    // h1 old (0/1)
  float h2o[4][HN];    // h2 old
  float h1n[4][HN];    // h1 new
  float uu [4][HN];    // staged uniforms (u1, then u2)
  float tmp[4][HN];    // nl-init redistribution buffer
  double lntab[17];    // ln(k/16), k=16..32  (built on device, ocml log_f64)
  double rcptab[17];   // CR(16/k)
};

// ---- bitwise replica of numpy's SIMD float32 exp ---------------------------
__device__ __forceinline__ float np_expf(float xf) {
  float q = __fmul_rn(xf, 1.442695040888963f);       // x * NPY_LOG2Ef
  q = __fadd_rn(q, 12582912.0f);                     // 0x1.8p23 round-to-even
  q = __fsub_rn(q, 12582912.0f);
  float x = __builtin_fmaf(q, -6.93145752e-1f, xf);  // Cody-Waite high
  x = __builtin_fmaf(q, -1.42860677e-6f, x);         // Cody-Waite low
  float num = __builtin_fmaf(x, 5.082762527590693718096e-04f,
                                6.757896990527504603057e-03f);
  num = __builtin_fmaf(num, x, 5.114512081637298353406e-02f);
  num = __builtin_fmaf(num, x, 2.473615434895520810817e-01f);
  num = __builtin_fmaf(num, x, 7.257664613233124478488e-01f);
  num = __builtin_fmaf(num, x, 9.999999999980870924916e-01f);
  float den = __builtin_fmaf(x, 2.159509375685829852307e-02f,
                                -2.742335390411667452936e-01f);
  den = __builtin_fmaf(den, x, 1.0f);
  float r = __fdiv_rn(num, den);
  int qi = (int)q;
  return __fmul_rn(r, __int_as_float((qi + 127) << 23));
}

// Custom fp64 log1p specialized to e in (0, 1] (e = np_expf(-|l|)).
// t = 1+e exact (e >= 2^-29 guarded); c = rint(16t)/16; s = (t-c)/c, |s|<=1/32;
// ln(1+s) degree-9 Horner + table ln(c). Forward rel err ~3e-15 -> fp32 result
// differs from the CR-fp64 path (round 7) with P~5e-8 per call.
__device__ __forceinline__ float np_log1pf(float ef, const double* __restrict__ lntab,
                                           const double* __restrict__ rcptab) {
  if (ef < 0x1p-29f) return ef;            // CR(log1p(e)) == e here (never taken in practice)
  double t  = 1.0 + (double)ef;            // exact
  double kd = rint(t * 16.0);              // k in [16, 32]
  int   idx = (int)kd - 16;
  double c  = kd * 0.0625;                 // exact
  double s  = (t - c) * rcptab[idx];       // t-c exact (Sterbenz)
  double p  = fma(s, 1.0/9.0, -0.125);
  p = fma(p, s,  1.0/7.0);
  p = fma(p, s, -1.0/6.0);
  p = fma(p, s,  1.0/5.0);
  p = fma(p, s, -0.25);
  p = fma(p, s,  1.0/3.0);
  p = fma(p, s, -0.5);
  p = fma(p, s,  1.0);
  p = p * s;                               // ln(1+s)
  return (float)(lntab[idx] + p);
}

// sigmoid-CE, numpy op order: (max(l,0) - l*label) + log1p(exp(-|l|))
__device__ __forceinline__ float ce32(float l, float label, const double* __restrict__ lntab,
                                      const double* __restrict__ rcptab) {
  float t3 = __fsub_rn(fmaxf(l, 0.0f), __fmul_rn(l, label));
  return __fadd_rn(t3, np_log1pf(np_expf(-fabsf(l)), lntab, rcptab));
}

// sigmoid = 1/(1+np.exp(-z)), IEEE divide
__device__ __forceinline__ float sig32(float z) {
  return __fdiv_rn(1.0f, __fadd_rn(1.0f, np_expf(-z)));
}

// numpy pairwise sum over 10 on lanes 0..9 (uniform result)
__device__ __forceinline__ float sum10(float c) {
  float c0 = __shfl(c, 0), c1 = __shfl(c, 1), c2 = __shfl(c, 2), c3 = __shfl(c, 3);
  float c4 = __shfl(c, 4), c5 = __shfl(c, 5), c6 = __shfl(c, 6), c7 = __shfl(c, 7);
  float c8 = __shfl(c, 8), c9 = __shfl(c, 9);
  float t = __fadd_rn(__fadd_rn(__fadd_rn(c0, c1), __fadd_rn(c2, c3)),
                      __fadd_rn(__fadd_rn(c4, c5), __fadd_rn(c6, c7)));
  t = __fadd_rn(t, c8);
  t = __fadd_rn(t, c9);
  return t;
}

// numpy pairwise sum over 256 children distributed 4/lane (see round 7).
__device__ __forceinline__ float fold256(const float c[4], int idx) {
  float r = __shfl(c[0], idx);
  r = __fadd_rn(r, __shfl(c[1], idx));
  r = __fadd_rn(r, __shfl(c[2], idx));
  r = __fadd_rn(r, __shfl(c[3], idx));
  r = __fadd_rn(r, __shfl(c[0], idx + 16));
  r = __fadd_rn(r, __shfl(c[1], idx + 16));
  r = __fadd_rn(r, __shfl(c[2], idx + 16));
  r = __fadd_rn(r, __shfl(c[3], idx + 16));
  r = __fadd_rn(r, __shfl(c[0], idx + 32));
  r = __fadd_rn(r, __shfl(c[1], idx + 32));
  r = __fadd_rn(r, __shfl(c[2], idx + 32));
  r = __fadd_rn(r, __shfl(c[3], idx + 32));
  r = __fadd_rn(r, __shfl(c[0], idx + 48));
  r = __fadd_rn(r, __shfl(c[1], idx + 48));
  r = __fadd_rn(r, __shfl(c[2], idx + 48));
  r = __fadd_rn(r, __shfl(c[3], idx + 48));
  r = __fadd_rn(r, __shfl_xor(r, 1));
  r = __fadd_rn(r, __shfl_xor(r, 2));
  r = __fadd_rn(r, __shfl_xor(r, 4));
  r = __fadd_rn(r, __shfl_xor(r, 8));
  return r;
}

__global__ __launch_bounds__(256) void stoch_mlp(
    const float* __restrict__ x,  const int* __restrict__ h1,
    const int* __restrict__ h2,   const int* __restrict__ y,
    const float* __restrict__ W1, const float* __restrict__ b1,
    const float* __restrict__ W2, const float* __restrict__ b2,
    const float* __restrict__ Wo, const float* __restrict__ bo,
    const float* __restrict__ u1, const float* __restrict__ u2,
    float* __restrict__ out)
{
  __shared__ Smem sm;
  const int t    = threadIdx.x;
  const int lane = t & 63;
  const int wid  = t >> 6;            // wave id == local batch row
  const int b0   = blockIdx.x * 4;
  const int b    = b0 + wid;

  // ---- phase 1: tables + stage states/uniforms; pl1 = x@W1 (BLAS fp32) ----
  if (t < 17) {
    double c = (double)(t + 16) * 0.0625;
    sm.lntab[t]  = log(c);            // ocml fp64 log, once per block
    sm.rcptab[t] = 16.0 / (double)(t + 16);
  }
  for (int j = lane; j < HN; j += 64) {
    sm.h1o[wid][j] = (float)h1[b * HN + j];
    sm.h2o[wid][j] = (float)h2[b * HN + j];
    sm.uu [wid][j] = u1[(size_t)j * NB + b];
  }
  {
    float a0 = 0.0f, a1 = 0.0f, a2 = 0.0f, a3 = 0.0f;   // sequential-k FMA chain
    const float* x0 = x + (size_t)b0 * DIN;
    for (int k = 0; k < DIN; ++k) {
      float wk = W1[k * HN + t];
      a0 = __builtin_fmaf(x0[k],           wk, a0);
      a1 = __builtin_fmaf(x0[DIN   + k],   wk, a1);
      a2 = __builtin_fmaf(x0[2*DIN + k],   wk, a2);
      a3 = __builtin_fmaf(x0[3*DIN + k],   wk, a3);
    }
    sm.pl[0][t] = __fadd_rn(a0, b1[t]);
    sm.pl[1][t] = __fadd_rn(a1, b1[t]);
    sm.pl[2][t] = __fadd_rn(a2, b1[t]);
    sm.pl[3][t] = __fadd_rn(a3, b1[t]);
  }
  __syncthreads();

  // nl-init = h1_old @ W2 + b2: masked fp32 adds == BLAS FMA chain bitwise
  {
    float acc[4] = {0.0f, 0.0f, 0.0f, 0.0f};
    for (int j = 0; j < HN; ++j) {
      if (sm.h1o[wid][j] != 0.0f) {
        float4 wf = *reinterpret_cast<const float4*>(W2 + (size_t)j * HN + 4*lane);
        acc[0] = __fadd_rn(acc[0], wf.x);  acc[1] = __fadd_rn(acc[1], wf.y);
        acc[2] = __fadd_rn(acc[2], wf.z);  acc[3] = __fadd_rn(acc[3], wf.w);
      }
    }
    float4 bv = *reinterpret_cast<const float4*>(b2 + 4*lane);
    sm.tmp[wid][4*lane + 0] = __fadd_rn(acc[0], bv.x);
    sm.tmp[wid][4*lane + 1] = __fadd_rn(acc[1], bv.y);
    sm.tmp[wid][4*lane + 2] = __fadd_rn(acc[2], bv.z);
    sm.tmp[wid][4*lane + 3] = __fadd_rn(acc[3], bv.w);
  }
  __syncthreads();

  const double* lntab  = sm.lntab;
  const double* rcptab = sm.rcptab;

  // ---- phase 2: layer-0 scan — 4 children per lane ------------------------
  // lane = 16*g + idx; chain idx = (half, jacc); lane owns m = 4g..4g+3:
  // child k(i) = half*128 + (4g+i)*8 + jacc
  const int idx  = lane & 15;
  const int g    = lane >> 4;
  const int half = idx >> 3;
  const int jacc = idx & 7;
  const int kb   = half * 128 + (4 * g) * 8 + jacc;   // + i*8

  float nlv[4], nv[4], wv[4];
  #pragma unroll
  for (int i = 0; i < 4; ++i) {
    int k = kb + i * 8;
    nlv[i] = sm.tmp[wid][k];
    nv[i]  = sm.h2o[wid][k];
    wv[i]  = W2[k];                    // prefetch row 0
  }
  float S_c;                           // carried-state CE sum (wave-uniform)
  {
    float ci[4];
    #pragma unroll
    for (int i = 0; i < 4; ++i) ci[i] = ce32(nlv[i], nv[i], lntab, rcptab);
    S_c = fold256(ci, idx);
  }

  {
    float nodeN = sm.h1o[wid][0], uN = sm.uu[wid][0], plN = sm.pl[wid][0];
    for (int j = 0; j < HN; ++j) {
      float node = nodeN, uj = uN, plj = plN;
      bool  nd   = (node != 0.0f);
      float wcur[4];
      #pragma unroll
      for (int i = 0; i < 4; ++i) wcur[i] = wv[i];
      if (j + 1 < HN) {
        nodeN = sm.h1o[wid][j + 1];
        uN    = sm.uu [wid][j + 1];
        plN   = sm.pl [wid][j + 1];
        #pragma unroll
        for (int i = 0; i < 4; ++i) wv[i] = W2[(size_t)(j + 1) * HN + kb + i * 8];
      }
      float one_m = __fsub_rn(1.0f, node);
      float nl0[4], nl1[4], chg[4];
      #pragma unroll
      for (int i = 0; i < 4; ++i) {
        nl0[i] = __fsub_rn(nlv[i], __fmul_rn(node,  wcur[i]));
        nl1[i] = __fadd_rn(nlv[i], __fmul_rn(one_m, wcur[i]));
        chg[i] = ce32(nd ? nl0[i] : nl1[i], nv[i], lntab, rcptab);  // fresh side
      }
      float F  = fold256(chg, idx);    // fresh-side CE sum, numpy order
      float S0 = nd ? F : S_c;         // stale side == carried sum bitwise
      float S1 = nd ? S_c : F;
      float z    = __fsub_rn(__fadd_rn(plj, -S1), -S0);   // (pl + lp1) - lp0
      float prob = sig32(z);
      bool  nw   = (uj < prob);
      #pragma unroll
      for (int i = 0; i < 4; ++i) nlv[i] = nw ? nl1[i] : nl0[i];
      S_c = (nw != nd) ? F : S_c;
      if (lane == 0) sm.h1n[wid][j] = nw ? 1.0f : 0.0f;
    }
  }
  __syncthreads();

  // ---- phase 3: pl2 = h1_new @ W2 + b2 (masked fp32 == BLAS chain) --------
  {
    float acc[4] = {0.0f, 0.0f, 0.0f, 0.0f};
    for (int j = 0; j < HN; ++j) {
      if (sm.h1n[wid][j] != 0.0f) {
        float4 wf = *reinterpret_cast<const float4*>(W2 + (size_t)j * HN + 4*lane);
        acc[0] = __fadd_rn(acc[0], wf.x);  acc[1] = __fadd_rn(acc[1], wf.y);
        acc[2] = __fadd_rn(acc[2], wf.z);  acc[3] = __fadd_rn(acc[3], wf.w);
      }
    }
    float4 bv = *reinterpret_cast<const float4*>(b2 + 4*lane);
    sm.pl[wid][4*lane + 0] = __fadd_rn(acc[0], bv.x);
    sm.pl[wid][4*lane + 1] = __fadd_rn(acc[1], bv.y);
    sm.pl[wid][4*lane + 2] = __fadd_rn(acc[2], bv.z);
    sm.pl[wid][4*lane + 3] = __fadd_rn(acc[3], bv.w);
  }
  for (int j = lane; j < HN; j += 64) sm.uu[wid][j] = u2[(size_t)j * NB + b];

  // layer-1 init: nlo = h2_old @ Wout + bout (masked fp32); nvy = y
  float nvy = 0.0f, nlo = 0.0f;
  if (lane < NOUT) {
    nvy = (float)y[b * NOUT + lane];
    float a = 0.0f;
    for (int j = 0; j < HN; ++j)
      if (sm.h2o[wid][j] != 0.0f) a = __fadd_rn(a, Wo[j * NOUT + lane]);
    nlo = __fadd_rn(a, bo[lane]);
  }
  float S_c1 = sum10((lane < NOUT) ? ce32(nlo, nvy, lntab, rcptab) : 0.0f);
  __syncthreads();

  // ---- phase 4: layer-1 scan (10 children on lanes 0..9) ------------------
  {
    float wnext = (lane < NOUT) ? Wo[lane] : 0.0f;
    for (int j = 0; j < HN; ++j) {
      float node = sm.h2o[wid][j];
      float uj   = sm.uu[wid][j];
      float plj  = sm.pl[wid][j];
      bool  nd   = (node != 0.0f);
      float w    = wnext;
      if (j + 1 < HN) wnext = (lane < NOUT) ? Wo[(j + 1) * NOUT + lane] : 0.0f;
      float one_m = __fsub_rn(1.0f, node);
      float nl0 = __fsub_rn(nlo, __fmul_rn(node,  w));
      float nl1 = __fadd_rn(nlo, __fmul_rn(one_m, w));
      float chg = (lane < NOUT) ? ce32(nd ? nl0 : nl1, nvy, lntab, rcptab) : 0.0f;
      float F   = sum10(chg);
      float S0  = nd ? F : S_c1;
      float S1  = nd ? S_c1 : F;
      float z    = __fsub_rn(__fadd_rn(plj, -S1), -S0);
      float prob = sig32(z);
      bool  nw   = (uj < prob);
      nlo  = nw ? nl1 : nl0;
      S_c1 = (nw != nd) ? F : S_c1;
      if (lane == 0) out[(size_t)b * OSTR + HN + j] = nw ? 1.0f : 0.0f;
    }
  }

  // ---- phase 5: outputs ---------------------------------------------------
  float* orow = out + (size_t)b * OSTR;
  for (int j = lane; j < HN; j += 64) orow[j] = sm.h1n[wid][j];
  if (lane < NOUT) orow[2*HN + lane] = nlo;
}

extern "C" void kernel_launch(void* const* d_in, const int* in_sizes, int n_in,
                              void* d_out, int out_size, void* d_ws, size_t ws_size,
                              hipStream_t stream) {
  const float* x  = (const float*)d_in[0];
  const int*   h1 = (const int*)  d_in[1];
  const int*   h2 = (const int*)  d_in[2];
  const int*   y  = (const int*)  d_in[3];
  const float* W1 = (const float*)d_in[4];
  const float* b1 = (const float*)d_in[5];
  const float* W2 = (const float*)d_in[6];
  const float* b2 = (const float*)d_in[7];
  const float* Wo = (const float*)d_in[8];
  const float* bo = (const float*)d_in[9];
  const float* u1 = (const float*)d_in[10];
  const float* u2 = (const float*)d_in[11];
  stoch_mlp<<<NB/4, 256, 0, stream>>>(x, h1, h2, y, W1, b1, W2, b2, Wo, bo, u1, u2,
                                      (float*)d_out);
}